// Round 16
// baseline (301.798 us; speedup 1.0000x reference)
//
#include <hip/hip_runtime.h>
#include <math.h>

typedef __attribute__((ext_vector_type(8))) _Float16 f16x8;
typedef __attribute__((ext_vector_type(16))) float f32x16;
typedef unsigned long long ull;

// ---------------- fp16 split2 helpers: v = h + l/4096 ----------------
__device__ __forceinline__ void split2(float v, _Float16& h, _Float16& l) {
  h = (_Float16)v;
  l = (_Float16)((v - (float)h) * 4096.0f);
}

// ---------------- workspace layout (byte offsets) ----------------
#define OFF_W1H  0UL          // 9*256*256*2 = 1179648
#define OFF_W1L  1179648UL
#define OFF_W2H  2359296UL
#define OFF_W2L  3538944UL
#define OFF_WRH  4718592UL    // 9*32*256*2 = 147456
#define OFF_WRL  4866048UL
#define OFF_I0H  5013504UL    // 2*4096*256*2 = 4194304  (aliased as conv2-out F after conv1)
#define OFF_I0L  9207808UL
#define OFF_I1H  13402112UL
#define OFF_I1L  14450688UL
#define OFF_I2H  15499264UL
#define OFF_I2L  15761408UL
#define OFF_L3F  16023552UL   // f32 CHW 2*256*1024*4 = 2097152
#define OFF_H0H  18120704UL
#define OFF_H0L  22315008UL
#define OFF_H1H  26509312UL
#define OFF_H1L  27557888UL
#define OFF_H2H  28606464UL
#define OFF_H2L  28868608UL
#define OFF_LOGITS 29130752UL // 2*16128*4 = 129024
#define OFF_TVALS  29259776UL // 516096
#define OFF_SKEY   29775872UL // 129024
#define OFF_COORDS 29904896UL // 3840
#define OFF_BN     29908992UL // 4096
#define OFF_HIST   29917184UL // 6*2048*4 = 49152
#define OFF_P0     29966336UL // 2 * 10752*256*4 = 22020096
#define WS_NEED2   51986432UL

// out layout: dets[2][3][32][5] @0 (960) | mask[2][3][32] @960 (192) | rois @1152

// ---------------- prep: weight split (coalesced) + BN fold + hist zero ----------------
__global__ __launch_bounds__(256) void prep_w_kernel(
    const float* __restrict__ hw1, const float* __restrict__ hw2,
    const float* __restrict__ clsw, const float* __restrict__ locw,
    const float* __restrict__ hg1, const float* __restrict__ hb1,
    const float* __restrict__ hm1, const float* __restrict__ hv1,
    const float* __restrict__ hg2, const float* __restrict__ hb2,
    const float* __restrict__ hm2, const float* __restrict__ hv2,
    char* __restrict__ ws)
{
  if (blockIdx.x == 0) {
    int t = threadIdx.x;
    float* inv1 = (float*)(ws + OFF_BN);
    float* beta1 = inv1 + 256;
    float* inv2 = inv1 + 512;
    float* beta2 = inv1 + 768;
    float i1 = (float)((double)hg1[t] / sqrt((double)hv1[t] + 1e-5));
    inv1[t] = i1;
    beta1[t] = hb1[t] - hm1[t] * i1;
    float i2 = (float)((double)hg2[t] / sqrt((double)hv2[t] + 1e-5));
    inv2[t] = i2;
    beta2[t] = hb2[t] - hm2[t] * i2;
  } else if (blockIdx.x <= 48) {
    ((unsigned int*)(ws + OFF_HIST))[(blockIdx.x - 1) * 256 + threadIdx.x] = 0u;
  }
  _Float16* w1h = (_Float16*)(ws + OFF_W1H);
  _Float16* w1l = (_Float16*)(ws + OFF_W1L);
  _Float16* w2h = (_Float16*)(ws + OFF_W2H);
  _Float16* w2l = (_Float16*)(ws + OFF_W2L);
  _Float16* wrh = (_Float16*)(ws + OFF_WRH);
  _Float16* wrl = (_Float16*)(ws + OFF_WRL);
  const int TOT2 = 2 * 65536 + 8192;   // (oc,ic) pairs
  for (int e = blockIdx.x * 256 + threadIdx.x; e < TOT2; e += gridDim.x * 256) {
    const float* src; _Float16 *dh, *dl; int di, plane;
    if (e < 65536) {
      src = hw1 + (size_t)e * 9; dh = w1h; dl = w1l; di = e; plane = 65536;
    } else if (e < 131072) {
      int e2 = e - 65536;
      src = hw2 + (size_t)e2 * 9; dh = w2h; dl = w2l; di = e2; plane = 65536;
    } else {
      int e3 = e - 131072;
      int oc = e3 >> 8;
      dh = wrh; dl = wrl; di = e3; plane = 8192;
      if (oc < 3) src = clsw + (size_t)e3 * 9;
      else if (oc < 15) src = locw + (size_t)(e3 - 768) * 9;
      else src = nullptr;
    }
    #pragma unroll
    for (int dydx = 0; dydx < 9; ++dydx) {
      float val = src ? src[dydx] : 0.f;
      _Float16 h, l;
      split2(val, h, l);
      dh[(size_t)dydx * plane + di] = h;
      dl[(size_t)dydx * plane + di] = l;
    }
  }
}

// ---------------- fuse body (shared by both fuse kernels) ----------------
__device__ __forceinline__ void fuse_body(
    float T[32][65],
    const float* __restrict__ a, const float* __restrict__ bUp,
    float* __restrict__ f32chw, _Float16* __restrict__ oH, _Float16* __restrict__ oL,
    int H, int logW, int bx, int img)
{
  int HW = H * H;
  const float* ap = a + (size_t)img * 256 * HW;
  const float* bp = bUp ? (bUp + (size_t)img * 256 * (HW >> 2)) : nullptr;
  float* fp = f32chw ? (f32chw + (size_t)img * 256 * HW) : nullptr;
  _Float16* oHp = oH + (size_t)img * HW * 256;
  _Float16* oLp = oL + (size_t)img * HW * 256;
  int p0 = bx * 64;
  int tid = threadIdx.x;
  int px = tid & 63, cg = tid >> 6;
  int gp = p0 + px;
  int y = gp >> logW, x = gp & (H - 1);
  int px2 = tid >> 2, q = tid & 3;
  for (int c0 = 0; c0 < 256; c0 += 32) {
    #pragma unroll
    for (int cc = 0; cc < 8; ++cc) {
      int c = c0 + cg * 8 + cc;
      float v = ap[(size_t)c * HW + gp];
      if (bp) v += bp[(size_t)c * (HW >> 2) + (y >> 1) * (H >> 1) + (x >> 1)];
      if (fp) fp[(size_t)c * HW + gp] = v;
      T[cg * 8 + cc][px] = v;
    }
    __syncthreads();
    {
      size_t oa = (size_t)(p0 + px2) * 256 + c0 + q * 8;
      f16x8 hs, ls;
      #pragma unroll
      for (int j = 0; j < 8; ++j) {
        float v = T[q * 8 + j][px2];
        _Float16 h, l;
        split2(v, h, l);
        hs[j] = h; ls[j] = l;
      }
      *(f16x8*)&oHp[oa] = hs;
      *(f16x8*)&oLp[oa] = ls;
    }
    __syncthreads();
  }
}

// merged small-level fuse: x<4 -> l4->i2 (H=16); x>=4 -> l3+up(l4)->i1,l3f (H=32)
__global__ __launch_bounds__(256) void fuse_small_kernel(
    const float* __restrict__ layer4, const float* __restrict__ layer3,
    float* __restrict__ l3f,
    _Float16* __restrict__ i2H, _Float16* __restrict__ i2L,
    _Float16* __restrict__ i1H, _Float16* __restrict__ i1L)
{
  __shared__ float T[32][65];
  int img = blockIdx.y;
  if (blockIdx.x < 4)
    fuse_body(T, layer4, nullptr, nullptr, i2H, i2L, 16, 4, blockIdx.x, img);
  else
    fuse_body(T, layer3, layer4, l3f, i1H, i1L, 32, 5, blockIdx.x - 4, img);
}

__global__ __launch_bounds__(256) void fuse_kernel(
    const float* __restrict__ a, const float* __restrict__ bUp,
    float* __restrict__ f32chw, _Float16* __restrict__ oH, _Float16* __restrict__ oL,
    int H, int logW)
{
  __shared__ float T[32][65];
  fuse_body(T, a, bUp, f32chw, oH, oL, H, logW, blockIdx.x, blockIdx.y);
}

// ---------------- MFMA implicit-GEMM 3x3 conv: 64px x 64oc per WAVE (round-10 body) ----------------
struct CArgs {
  const _Float16* inH[3]; const _Float16* inL[3];   // fp16 HWC per level
  const _Float16* wH; const _Float16* wL;           // [9][OCW][256]
  _Float16* outH[3]; _Float16* outL[3];             // fp16 HWC outs (mode 0, parts==1)
  const float* inv; const float* beta;              // BN folded
  float* logits; float* tvals;                      // mode 2, parts==1
  float* pbase; size_t pstride;                     // partial buffers (parts>1)
  int mode; int parts;
};

#define PXS 40   // LDS pixel stride in shorts (round-10 value)

template<int OCW, int WN, int NI>
__global__ __launch_bounds__(WN * 64, 2) void conv_mfma_kernel(CArgs a)
{
  constexpr int NT = WN * 64;
  constexpr int NOC = WN * NI * 32;
  constexpr int OCG = OCW / NOC;
  __shared__ _Float16 Ph[2][100 * PXS], Pl[2][100 * PXS];

  int bt = blockIdx.x;
  int lvl, tile;
  if (bt < 64) { lvl = 0; tile = bt; }
  else if (bt < 80) { lvl = 1; tile = bt - 64; }
  else { lvl = 2; tile = bt - 80; }
  int H = (lvl == 0) ? 64 : ((lvl == 1) ? 32 : 16);
  int HW = H * H;
  int tpr = H >> 3;
  int ty0 = (tile / tpr) * 8, tx0 = (tile % tpr) * 8;
  int img = blockIdx.z;

  int part = blockIdx.y / OCG;
  int ocb = (blockIdx.y % OCG) * NOC;
  int nicb = 8 / a.parts;
  int icb0 = part * nicb;
  float* pout = (a.parts > 1) ? (a.pbase + (size_t)part * a.pstride) : nullptr;

  const _Float16* inH = a.inH[lvl] + (size_t)img * HW * 256;
  const _Float16* inL = a.inL[lvl] + (size_t)img * HW * 256;

  int tid = threadIdx.x;
  int lane = tid & 63, wn = tid >> 6;
  int row = lane & 31, khalf = lane >> 5;
  int abase[2];
  #pragma unroll
  for (int mi = 0; mi < 2; ++mi) {
    int m = mi * 32 + row;
    abase[mi] = ((m >> 3) * 10 + (m & 7)) * PXS + khalf * 8;
  }

  const _Float16* wHb = a.wH + (size_t)(ocb + wn * NI * 32 + row) * 256 + khalf * 8 + icb0 * 32;
  const _Float16* wLb = a.wL + (size_t)(ocb + wn * NI * 32 + row) * 256 + khalf * 8 + icb0 * 32;

  f32x16 acc1[2][NI], acc2[2][NI];
  #pragma unroll
  for (int mi = 0; mi < 2; ++mi)
    #pragma unroll
    for (int ni = 0; ni < NI; ++ni)
      #pragma unroll
      for (int j = 0; j < 16; ++j) { acc1[mi][ni][j] = 0.f; acc2[mi][ni][j] = 0.f; }

  auto stage = [&](int icb, int buf) {
    for (int u = tid; u < 400; u += NT) {
      int pxl = u >> 2, icq = u & 3;
      int py = pxl / 10, pxx = pxl - py * 10;
      int gy = ty0 + py - 1, gx = tx0 + pxx - 1;
      int lo = pxl * PXS + icq * 8;
      if ((unsigned)gy < (unsigned)H && (unsigned)gx < (unsigned)H) {
        size_t ga = (size_t)(gy * H + gx) * 256 + icb * 32 + icq * 8;
        *(f16x8*)&Ph[buf][lo] = *(const f16x8*)&inH[ga];
        *(f16x8*)&Pl[buf][lo] = *(const f16x8*)&inL[ga];
      } else {
        f16x8 z;
        #pragma unroll
        for (int j = 0; j < 8; ++j) z[j] = (_Float16)0.f;
        *(f16x8*)&Ph[buf][lo] = z;
        *(f16x8*)&Pl[buf][lo] = z;
      }
    }
  };

  stage(icb0, 0);
  __syncthreads();

  for (int rel = 0; rel < nicb; ++rel) {
    int cur = rel & 1;
    if (rel < nicb - 1) stage(icb0 + rel + 1, cur ^ 1);
    #pragma unroll
    for (int dydx = 0; dydx < 9; ++dydx) {
      int sh = ((dydx / 3) * 10 + (dydx % 3)) * PXS;
      #pragma unroll
      for (int k2 = 0; k2 < 2; ++k2) {
        f16x8 bh[NI], bl[NI], ah[2], al[2];
        #pragma unroll
        for (int ni = 0; ni < NI; ++ni) {
          size_t ga = (size_t)dydx * OCW * 256 + (size_t)ni * 32 * 256 + rel * 32 + k2 * 16;
          bh[ni] = *(const f16x8*)&wHb[ga];
          bl[ni] = *(const f16x8*)&wLb[ga];
        }
        #pragma unroll
        for (int mi = 0; mi < 2; ++mi) {
          int off = abase[mi] + sh + k2 * 16;
          ah[mi] = *(const f16x8*)&Ph[cur][off];
          al[mi] = *(const f16x8*)&Pl[cur][off];
        }
        #pragma unroll
        for (int mi = 0; mi < 2; ++mi)
          #pragma unroll
          for (int ni = 0; ni < NI; ++ni) {
            acc1[mi][ni] = __builtin_amdgcn_mfma_f32_32x32x16_f16(ah[mi], bh[ni], acc1[mi][ni], 0, 0, 0);
            acc2[mi][ni] = __builtin_amdgcn_mfma_f32_32x32x16_f16(ah[mi], bl[ni], acc2[mi][ni], 0, 0, 0);
            acc2[mi][ni] = __builtin_amdgcn_mfma_f32_32x32x16_f16(al[mi], bh[ni], acc2[mi][ni], 0, 0, 0);
          }
      }
    }
    __syncthreads();
  }

  // ---- epilogue ----
  int poffv = (lvl == 0) ? 0 : ((lvl == 1) ? 4096 : 5120);
  #pragma unroll
  for (int mi = 0; mi < 2; ++mi)
    #pragma unroll
    for (int ni = 0; ni < NI; ++ni) {
      int oc = ocb + wn * NI * 32 + ni * 32 + row;
      float v[16];
      #pragma unroll
      for (int r = 0; r < 16; ++r) v[r] = acc1[mi][ni][r] + acc2[mi][ni][r] * (1.f / 4096.f);
      if (pout) {
        float* pp = pout + (size_t)(img * 5376 + poffv) * OCW;
        #pragma unroll
        for (int r = 0; r < 16; ++r) {
          int ml = (r & 3) + 8 * (r >> 2) + 4 * khalf;
          int m = mi * 32 + ml;
          int y = ty0 + (m >> 3), x = tx0 + (m & 7);
          __builtin_nontemporal_store(v[r], &pp[(size_t)(y * H + x) * OCW + oc]);
        }
      } else if (a.mode == 0) {
        _Float16* outH = a.outH[lvl] + (size_t)img * HW * 256;
        _Float16* outL = a.outL[lvl] + (size_t)img * HW * 256;
        float iv = a.inv[oc], bb = a.beta[oc];
        #pragma unroll
        for (int r = 0; r < 16; ++r) {
          int ml = (r & 3) + 8 * (r >> 2) + 4 * khalf;
          int m = mi * 32 + ml;
          int y = ty0 + (m >> 3), x = tx0 + (m & 7);
          float vv = v[r] * iv + bb;
          vv = (vv >= 0.f) ? vv : 0.01f * vv;
          _Float16 h, l;
          split2(vv, h, l);
          size_t oa = (size_t)(y * H + x) * 256 + oc;
          outH[oa] = h;
          outL[oa] = l;
        }
      } else {
        if (oc < 15) {
          int abse = (lvl == 0) ? 0 : ((lvl == 1) ? 12288 : 15360);
          #pragma unroll
          for (int r = 0; r < 16; ++r) {
            int ml = (r & 3) + 8 * (r >> 2) + 4 * khalf;
            int m = mi * 32 + ml;
            int y = ty0 + (m >> 3), x = tx0 + (m & 7);
            int gi = img * 16128 + abse + (y * H + x) * 3;
            if (oc < 3) a.logits[gi + oc] = v[r];
            else { int r2 = oc - 3; a.tvals[(size_t)(gi + (r2 >> 2)) * 4 + (r2 & 3)] = v[r]; }
          }
        }
      }
    }
}

// ---------------- combine: p0+p1 -> BN -> lrelu -> split2 HWC (fixed 2-part) ----------------
__global__ __launch_bounds__(256) void combine_head_kernel(
    const float* __restrict__ p0, const float* __restrict__ p1,
    const float* __restrict__ inv, const float* __restrict__ beta,
    _Float16* __restrict__ oH0, _Float16* __restrict__ oL0,
    _Float16* __restrict__ oH1, _Float16* __restrict__ oL1,
    _Float16* __restrict__ oH2, _Float16* __restrict__ oL2)
{
  int g = blockIdx.x * 256 + threadIdx.x;      // 10752*32 total
  int pixel = g >> 5, q = g & 31;
  size_t base = (size_t)pixel * 256 + q * 8;
  int img = pixel / 5376, rem = pixel - img * 5376;
  int lvl = (rem < 4096) ? 0 : ((rem < 5120) ? 1 : 2);
  int poffv = (lvl == 0) ? 0 : ((lvl == 1) ? 4096 : 5120);
  int HW = (lvl == 0) ? 4096 : ((lvl == 1) ? 1024 : 256);
  int lpx = rem - poffv;
  size_t oa = ((size_t)img * HW + lpx) * 256 + q * 8;
  _Float16* oH = ((lvl == 0) ? oH0 : ((lvl == 1) ? oH1 : oH2)) + oa;
  _Float16* oL = ((lvl == 0) ? oL0 : ((lvl == 1) ? oL1 : oL2)) + oa;
  f16x8 hs, ls;
  #pragma unroll
  for (int j = 0; j < 8; ++j) {
    int oc = q * 8 + j;
    float a0 = __builtin_nontemporal_load(&p0[base + j]);
    float a1 = __builtin_nontemporal_load(&p1[base + j]);
    float vv = (a0 + a1) * inv[oc] + beta[oc];
    vv = (vv >= 0.f) ? vv : 0.01f * vv;
    _Float16 h, l;
    split2(vv, h, l);
    hs[j] = h; ls[j] = l;
  }
  *(f16x8*)oH = hs;
  *(f16x8*)oL = ls;
}

// ---------------- decode helper ----------------
__device__ __forceinline__ void decode_one4(const float t0, const float t1,
                                            const float t2v, const float t3v,
                                            const float* __restrict__ anch, int i,
                                            float& x1, float& y1, float& x2, float& y2)
{
  float a0 = anch[i * 4 + 0], a1 = anch[i * 4 + 1], a2 = anch[i * 4 + 2], a3 = anch[i * 4 + 3];
  float aw = a2 - a0, ah = a3 - a1;
  float xx = a0 + t0 * aw;
  float yy = a1 + t1 * ah;
  float bw = aw * expf(t2v);
  float bh = ah * expf(t3v);
  x1 = fminf(fmaxf(xx, 0.f), 512.f);
  y1 = fminf(fmaxf(yy, 0.f), 512.f);
  x2 = fminf(fmaxf(xx + bw, 0.f), 512.f);
  y2 = fminf(fmaxf(yy + bh, 0.f), 512.f);
}

__device__ __forceinline__ void decode_one(const float* __restrict__ anch,
                                           const float* __restrict__ tv, int i,
                                           float& x1, float& y1, float& x2, float& y2)
{
  decode_one4(tv[i * 4 + 0], tv[i * 4 + 1], tv[i * 4 + 2], tv[i * 4 + 3], anch, i, x1, y1, x2, y2);
}

// ---------------- score kernel: (optional rpn-combine) + keys + 2048-bin hist ----------------
__global__ __launch_bounds__(256) void score_kernel(
    const float* __restrict__ logits, float* __restrict__ tvals,
    const float* __restrict__ praw,
    const float* __restrict__ anch0, const float* __restrict__ anch1, const float* __restrict__ anch2,
    unsigned int* __restrict__ skey, unsigned int* __restrict__ hist)
{
  int g = blockIdx.x * 256 + threadIdx.x;
  if (g >= 2 * 16128) return;
  int img = g / 16128, r = g - img * 16128;
  int lvl = (r < 12288) ? 0 : ((r < 15360) ? 1 : 2);
  int abase = (lvl == 0) ? 0 : ((lvl == 1) ? 12288 : 15360);
  int stride = (lvl == 0) ? 8 : ((lvl == 1) ? 16 : 32);
  const float* anch = (lvl == 0) ? anch0 : ((lvl == 1) ? anch1 : anch2);
  int i = r - abase;
  float lv, t0, t1, t2v, t3v;
  if (praw) {
    // combine rpn partials inline: pixel p = i/3, anchor a = i%3
    int poffv = (lvl == 0) ? 0 : ((lvl == 1) ? 4096 : 5120);
    int p = i / 3, a = i - p * 3;
    size_t pb = ((size_t)(img * 5376 + poffv) + p) * 32;
    float s[5] = {0.f, 0.f, 0.f, 0.f, 0.f};
    #pragma unroll
    for (int k = 0; k < 4; ++k) {
      const float* pp = praw + (size_t)k * 10752 * 32 + pb;
      s[0] += __builtin_nontemporal_load(&pp[a]);
      #pragma unroll
      for (int c = 0; c < 4; ++c) s[1 + c] += __builtin_nontemporal_load(&pp[3 + a * 4 + c]);
    }
    lv = s[0]; t0 = s[1]; t1 = s[2]; t2v = s[3]; t3v = s[4];
    float* tw = tvals + (size_t)g * 4;
    tw[0] = t0; tw[1] = t1; tw[2] = t2v; tw[3] = t3v;
  } else {
    lv = logits[g];
    const float* tv = tvals + (size_t)g * 4;
    t0 = tv[0]; t1 = tv[1]; t2v = tv[2]; t3v = tv[3];
  }
  float sc = 1.f / (1.f + expf(-lv));
  float x1, y1, x2, y2;
  decode_one4(t0, t1, t2v, t3v, anch, i, x1, y1, x2, y2);
  float minsz = 2.0f * (float)stride;
  bool valid = (sc > 0.5f) && ((x2 - x1) >= minsz) && ((y2 - y1) >= minsz);
  unsigned int key = valid ? __float_as_uint(sc) : 0u;
  skey[g] = key;
  if (valid)
    atomicAdd(&hist[(img * 3 + lvl) * 2048 + ((key & 0xFFFFFFu) >> 13)], 1u);
}

// ---------------- postproc: bin-threshold -> collect -> rank-sort -> ballot NMS -> outputs ----------------
__global__ __launch_bounds__(256) void postproc_kernel(
    const float* __restrict__ tvals,
    const float* __restrict__ anch0, const float* __restrict__ anch1, const float* __restrict__ anch2,
    const unsigned int* __restrict__ skey, const unsigned int* __restrict__ hist,
    float* __restrict__ dout, int* __restrict__ coords)
{
  int lvl = blockIdx.x, img = blockIdx.y;
  int N = (lvl == 0) ? 12288 : ((lvl == 1) ? 3072 : 768);
  int stride = (lvl == 0) ? 8 : ((lvl == 1) ? 16 : 32);
  int abase = (lvl == 0) ? 0 : ((lvl == 1) ? 12288 : 15360);
  const float* anch = (lvl == 0) ? anch0 : ((lvl == 1) ? anch1 : anch2);
  const float* tv = tvals + (size_t)(img * 16128 + abase) * 4;
  const unsigned int* sk = skey + img * 16128 + abase;
  int tx = threadIdx.x;

  __shared__ int tot[256];
  __shared__ int sh_bin, sh_V;
  __shared__ ull slist[1024];
  __shared__ int scnt;
  __shared__ ull skey64[256];
  __shared__ float bx0[256], bx1[256], bx2[256], bx3[256], bar[256], bsc[256];
  __shared__ ull colT[256][4];
  __shared__ ull kinit[4], kfin[4];
  __shared__ unsigned char bkeepArr[256];
  __shared__ int sel[32];

  const unsigned int* hp = hist + (img * 3 + lvl) * 2048;
  unsigned int hloc[8];
  #pragma unroll
  for (int j = 0; j < 8; ++j) hloc[j] = hp[tx * 8 + j];
  int sl[9]; sl[8] = 0;
  #pragma unroll
  for (int j = 7; j >= 0; --j) sl[j] = sl[j + 1] + (int)hloc[j];
  tot[tx] = sl[0];
  if (tx == 0) { sh_bin = 2048; scnt = 0; }
  __syncthreads();
  int T = 0;
  for (int b = 0; b < 256; ++b) T += (b > tx) ? tot[b] : 0;
  if (tx == 0) sh_V = T + sl[0];
  __syncthreads();
  int V = sh_V;
  int needed = (V < 256) ? V : 256;
  if (needed > 0) {
    #pragma unroll
    for (int j = 0; j < 8; ++j) {
      int suf = T + sl[j];
      int sufn = (j < 7) ? (T + sl[j + 1]) : T;
      if (suf >= needed && sufn < needed) sh_bin = tx * 8 + j;
    }
  }
  #pragma unroll
  for (int q = 0; q < 4; ++q) slist[tx + q * 256] = 0ull;
  __syncthreads();
  int Bstar = sh_bin;

  if (needed > 0) {
    const uint4* sk4 = (const uint4*)sk;
    for (int i4 = tx; i4 < (N >> 2); i4 += 256) {
      uint4 v4 = sk4[i4];
      unsigned int vv[4] = {v4.x, v4.y, v4.z, v4.w};
      #pragma unroll
      for (int q = 0; q < 4; ++q) {
        unsigned int v = vv[q];
        if (v != 0u && (int)((v & 0xFFFFFFu) >> 13) >= Bstar) {
          int p = atomicAdd(&scnt, 1);
          if (p < 1024)
            slist[p] = ((ull)v << 32) | (ull)(0xFFFFFFFFu - (unsigned)(i4 * 4 + q));
        }
      }
    }
  }
  __syncthreads();
  int M = scnt < 1024 ? scnt : 1024;

  skey64[tx] = 0ull;
  __syncthreads();
  for (int it = tx; it < M; it += 256) {
    ull K = slist[it];
    int rank = 0;
    for (int j = 0; j < M; ++j) rank += (slist[j] > K) ? 1 : 0;
    if (rank < 256) skey64[rank] = K;
  }
  __syncthreads();

  {
    ull key = skey64[tx];
    float x1 = 0.f, y1 = 0.f, x2 = 0.f, y2 = 0.f, sc = 0.f;
    if (key != 0ull) {
      sc = __uint_as_float((unsigned int)(key >> 32));
      int idx = (int)(0xFFFFFFFFu - (unsigned int)(key & 0xFFFFFFFFull));
      decode_one(anch, tv, idx, x1, y1, x2, y2);
    }
    bx0[tx] = x1; bx1[tx] = y1; bx2[tx] = x2; bx3[tx] = y2;
    bsc[tx] = sc;
    bar[tx] = (x2 - x1 + 1.f) * (y2 - y1 + 1.f);
    ull b = __ballot(sc > 0.5f);
    if ((tx & 63) == 0) kinit[tx >> 6] = b;
  }
  __syncthreads();

  {
    float xj1 = bx0[tx], yj1 = bx1[tx], xj2 = bx2[tx], yj2 = bx3[tx], aj = bar[tx];
    #pragma unroll
    for (int w = 0; w < 4; ++w) {
      ull rr = 0ull;
      int j0 = w * 64;
      int ie = (tx < j0 + 64) ? tx : (j0 + 64);
      for (int i = j0; i < ie; ++i) {
        float xx1 = fmaxf(xj1, bx0[i]);
        float yy1 = fmaxf(yj1, bx1[i]);
        float xx2 = fminf(xj2, bx2[i]);
        float yy2 = fminf(yj2, bx3[i]);
        float ww = fmaxf(0.f, xx2 - xx1 + 1.f);
        float hh = fmaxf(0.f, yy2 - yy1 + 1.f);
        float inter = ww * hh;
        float ovr = inter / (aj + bar[i] - inter);
        rr |= (ovr > 0.3f) ? (1ull << (i & 63)) : 0ull;
      }
      colT[tx][w] = rr;
    }
  }
  __syncthreads();

  if (tx < 64) {
    int l = tx;
    ull cm[4][4];
    #pragma unroll
    for (int c = 0; c < 4; ++c)
      #pragma unroll
      for (int w = 0; w < 4; ++w) cm[c][w] = colT[l + 64 * c][w];
    int av[4];
    #pragma unroll
    for (int c = 0; c < 4; ++c) av[c] = (int)((kinit[c] >> l) & 1ull);
    for (int cw = 0; cw < 4; ++cw) {
      ull rem = __ballot(av[cw] != 0);
      while (rem) {
        int ib = __builtin_ctzll(rem);
        #pragma unroll
        for (int c = 0; c < 4; ++c) {
          int sup = (int)((cm[c][cw] >> ib) & 1ull);
          av[c] &= sup ^ 1;
        }
        ull ready = __ballot(av[cw] != 0);
        rem = (ib == 63) ? 0ull : (ready & (~0ull << (ib + 1)));
      }
    }
    #pragma unroll
    for (int c = 0; c < 4; ++c) {
      ull bw = __ballot(av[c] != 0);
      if (l == 0) kfin[c] = bw;
      bkeepArr[l + 64 * c] = (unsigned char)av[c];
    }
  }
  __syncthreads();

  {
    int r = tx;
    int m = bkeepArr[r];
    int K = 0, before = 0;
    #pragma unroll
    for (int c = 0; c < 4; ++c) {
      int pc = __popcll(kfin[c]);
      K += pc;
      if (r >= (c + 1) * 64) before += pc;
      else if (r > c * 64) before += __popcll(kfin[c] & ((1ull << (r - c * 64)) - 1ull));
    }
    int rank = m ? before : (K + r - before);
    if (rank < 32) sel[rank] = r;
  }
  __syncthreads();

  if (tx < 32) {
    int r = sel[tx];
    int m = bkeepArr[r];
    int ob = (img * 3 + lvl) * 32 + tx;
    float d0 = 0.f, d1 = 0.f, d2 = 0.f, d3 = 0.f, d4 = 0.f;
    int c0 = 0, c1 = 0, c2 = 2, c3 = 2;
    if (m) {
      d0 = bx0[r]; d1 = bx1[r]; d2 = bx2[r]; d3 = bx3[r]; d4 = bsc[r];
      c0 = ((int)d0) / stride; c1 = ((int)d1) / stride;
      c2 = ((int)d2) / stride; c3 = ((int)d3) / stride;
    }
    dout[ob * 5 + 0] = d0; dout[ob * 5 + 1] = d1; dout[ob * 5 + 2] = d2;
    dout[ob * 5 + 3] = d3; dout[ob * 5 + 4] = d4;
    dout[960 + ob] = m ? 1.f : 0.f;
    coords[ob * 5 + 0] = c0; coords[ob * 5 + 1] = c1;
    coords[ob * 5 + 2] = c2; coords[ob * 5 + 3] = c3;
    coords[ob * 5 + 4] = m;
  }
}

// ---------------- ROI adaptive 7x7 maxpool: one block per (roi, bin) ----------------
__global__ __launch_bounds__(256) void roipool_kernel(
    const _Float16* __restrict__ fh0, const _Float16* __restrict__ fl0,
    const _Float16* __restrict__ fh1, const _Float16* __restrict__ fl1,
    const _Float16* __restrict__ fh2, const _Float16* __restrict__ fl2,
    const int* __restrict__ coords, float* __restrict__ dout)
{
  int bx = blockIdx.x;
  int slot = bx / 49, bin = bx - slot * 49;
  int yi = bin / 7, xi = bin - yi * 7;
  int lvl = blockIdx.y, img = blockIdx.z;
  int ob = (img * 3 + lvl) * 32 + slot;
  int c = threadIdx.x;
  const int* cw = coords + ob * 5;
  float* outp = dout + 1152 + (size_t)ob * 256 * 49 + (size_t)c * 49 + yi * 7 + xi;
  int m = cw[4];
  if (!m) { *outp = 0.f; return; }
  int H = (lvl == 0) ? 64 : ((lvl == 1) ? 32 : 16);
  const _Float16* fh = ((lvl == 0) ? fh0 : ((lvl == 1) ? fh1 : fh2)) + (size_t)img * H * H * 256;
  const _Float16* fl = ((lvl == 0) ? fl0 : ((lvl == 1) ? fl1 : fl2)) + (size_t)img * H * H * 256;
  int lox = cw[0], loy = cw[1], hix = cw[2], hiy = cw[3];
  int Lx = hix - lox, Ly = hiy - loy;
  int ys = loy + (yi * Ly) / 7;
  int ye = loy + ((yi + 1) * Ly + 6) / 7;
  int xs = lox + (xi * Lx) / 7;
  int xe = lox + ((xi + 1) * Lx + 6) / 7;
  float mx = -3.402823466e+38f;
  for (int y = ys; y < ye; ++y) {
    size_t rowb = ((size_t)y * H) * 256 + c;
    for (int x = xs; x < xe; ++x) {
      size_t idx = rowb + (size_t)x * 256;
      float v = (float)fh[idx] + (float)fl[idx] * (1.f / 4096.f);
      mx = fmaxf(mx, v);
    }
  }
  *outp = mx;
}

// ---------------- host ----------------
extern "C" void kernel_launch(void* const* d_in, const int* in_sizes, int n_in,
                              void* d_out, int out_size, void* d_ws, size_t ws_size,
                              hipStream_t stream)
{
  (void)in_sizes; (void)n_in; (void)out_size;
  char* ws = (char*)d_ws;
  const float* layer2 = (const float*)d_in[0];
  const float* layer3 = (const float*)d_in[1];
  const float* layer4 = (const float*)d_in[2];
  const float* anch2  = (const float*)d_in[3];
  const float* anch3  = (const float*)d_in[4];
  const float* anch4  = (const float*)d_in[5];
  const float* hw1 = (const float*)d_in[6];
  const float* hg1 = (const float*)d_in[7];
  const float* hb1 = (const float*)d_in[8];
  const float* hm1 = (const float*)d_in[9];
  const float* hv1 = (const float*)d_in[10];
  const float* hw2 = (const float*)d_in[11];
  const float* hg2 = (const float*)d_in[12];
  const float* hb2 = (const float*)d_in[13];
  const float* hm2 = (const float*)d_in[14];
  const float* hv2 = (const float*)d_in[15];
  const float* clsw = (const float*)d_in[16];
  const float* locw = (const float*)d_in[17];
  float* dout = (float*)d_out;

  int hparts = (ws_size >= WS_NEED2) ? 2 : 1;
  int rparts = (ws_size >= WS_NEED2) ? 4 : 1;

  _Float16* i0H = (_Float16*)(ws + OFF_I0H);
  _Float16* i0L = (_Float16*)(ws + OFF_I0L);
  _Float16* i1H = (_Float16*)(ws + OFF_I1H);
  _Float16* i1L = (_Float16*)(ws + OFF_I1L);
  _Float16* i2H = (_Float16*)(ws + OFF_I2H);
  _Float16* i2L = (_Float16*)(ws + OFF_I2L);
  float* l3f = (float*)(ws + OFF_L3F);
  _Float16* h0H = (_Float16*)(ws + OFF_H0H);
  _Float16* h0L = (_Float16*)(ws + OFF_H0L);
  _Float16* h1H = (_Float16*)(ws + OFF_H1H);
  _Float16* h1L = (_Float16*)(ws + OFF_H1L);
  _Float16* h2H = (_Float16*)(ws + OFF_H2H);
  _Float16* h2L = (_Float16*)(ws + OFF_H2L);
  float* logits = (float*)(ws + OFF_LOGITS);
  float* tvals  = (float*)(ws + OFF_TVALS);
  unsigned int* skey = (unsigned int*)(ws + OFF_SKEY);
  int* coords = (int*)(ws + OFF_COORDS);
  float* bn = (float*)(ws + OFF_BN);
  float* inv1 = bn; float* beta1 = bn + 256; float* inv2 = bn + 512; float* beta2 = bn + 768;
  unsigned int* hist = (unsigned int*)(ws + OFF_HIST);
  float* P0 = (float*)(ws + OFF_P0);
  float* P1 = P0 + 10752UL * 256UL;

  prep_w_kernel<<<576, 256, 0, stream>>>(hw1, hw2, clsw, locw,
                                         hg1, hb1, hm1, hv1, hg2, hb2, hm2, hv2, ws);

  fuse_small_kernel<<<dim3(20, 2), 256, 0, stream>>>(layer4, layer3, l3f, i2H, i2L, i1H, i1L);
  fuse_kernel<<<dim3(64, 2), 256, 0, stream>>>(layer2, l3f, nullptr, i0H, i0L, 64, 6);

  CArgs c1;
  c1.inH[0] = i0H; c1.inH[1] = i1H; c1.inH[2] = i2H;
  c1.inL[0] = i0L; c1.inL[1] = i1L; c1.inL[2] = i2L;
  c1.wH = (const _Float16*)(ws + OFF_W1H); c1.wL = (const _Float16*)(ws + OFF_W1L);
  c1.outH[0] = h0H; c1.outH[1] = h1H; c1.outH[2] = h2H;
  c1.outL[0] = h0L; c1.outL[1] = h1L; c1.outL[2] = h2L;
  c1.inv = inv1; c1.beta = beta1;
  c1.logits = nullptr; c1.tvals = nullptr;
  c1.pbase = P0; c1.pstride = 10752UL * 256UL;
  c1.mode = 0; c1.parts = hparts;
  conv_mfma_kernel<256, 2, 2><<<dim3(84, hparts * 2, 2), 128, 0, stream>>>(c1);
  if (hparts > 1)
    combine_head_kernel<<<1344, 256, 0, stream>>>(P0, P1, inv1, beta1,
                                                  h0H, h0L, h1H, h1L, h2H, h2L);

  _Float16* f0H = i0H; _Float16* f0L = i0L;
  _Float16* f1H = i1H; _Float16* f1L = i1L;
  _Float16* f2H = i2H; _Float16* f2L = i2L;

  CArgs c2;
  c2.inH[0] = h0H; c2.inH[1] = h1H; c2.inH[2] = h2H;
  c2.inL[0] = h0L; c2.inL[1] = h1L; c2.inL[2] = h2L;
  c2.wH = (const _Float16*)(ws + OFF_W2H); c2.wL = (const _Float16*)(ws + OFF_W2L);
  c2.outH[0] = f0H; c2.outH[1] = f1H; c2.outH[2] = f2H;
  c2.outL[0] = f0L; c2.outL[1] = f1L; c2.outL[2] = f2L;
  c2.inv = inv2; c2.beta = beta2;
  c2.logits = nullptr; c2.tvals = nullptr;
  c2.pbase = P0; c2.pstride = 10752UL * 256UL;
  c2.mode = 0; c2.parts = hparts;
  conv_mfma_kernel<256, 2, 2><<<dim3(84, hparts * 2, 2), 128, 0, stream>>>(c2);
  if (hparts > 1)
    combine_head_kernel<<<1344, 256, 0, stream>>>(P0, P1, inv2, beta2,
                                                  f0H, f0L, f1H, f1L, f2H, f2L);

  CArgs cr;
  cr.inH[0] = f0H; cr.inH[1] = f1H; cr.inH[2] = f2H;
  cr.inL[0] = f0L; cr.inL[1] = f1L; cr.inL[2] = f2L;
  cr.wH = (const _Float16*)(ws + OFF_WRH); cr.wL = (const _Float16*)(ws + OFF_WRL);
  cr.outH[0] = nullptr; cr.outH[1] = nullptr; cr.outH[2] = nullptr;
  cr.outL[0] = nullptr; cr.outL[1] = nullptr; cr.outL[2] = nullptr;
  cr.inv = nullptr; cr.beta = nullptr;
  cr.logits = logits; cr.tvals = tvals;
  cr.pbase = P0; cr.pstride = 10752UL * 32UL;
  cr.mode = 2; cr.parts = rparts;
  conv_mfma_kernel<32, 1, 1><<<dim3(84, rparts, 2), 64, 0, stream>>>(cr);

  score_kernel<<<126, 256, 0, stream>>>(logits, tvals, (rparts > 1) ? P0 : nullptr,
                                        anch2, anch3, anch4, skey, hist);
  postproc_kernel<<<dim3(3, 2), 256, 0, stream>>>(tvals, anch2, anch3, anch4, skey, hist, dout, coords);
  roipool_kernel<<<dim3(32 * 49, 3, 2), 256, 0, stream>>>(f0H, f0L, f1H, f1L, f2H, f2L, coords, dout);
}

// Round 17
// 299.713 us; speedup vs baseline: 1.0070x; 1.0070x over previous
//
#include <hip/hip_runtime.h>
#include <math.h>

typedef __attribute__((ext_vector_type(8))) _Float16 f16x8;
typedef __attribute__((ext_vector_type(16))) float f32x16;
typedef unsigned long long ull;

// ---------------- fp16 split2 helpers: v = h + l/4096 ----------------
__device__ __forceinline__ void split2(float v, _Float16& h, _Float16& l) {
  h = (_Float16)v;
  l = (_Float16)((v - (float)h) * 4096.0f);
}

// ---------------- workspace layout (byte offsets) ----------------
#define OFF_W1H  0UL          // 9*256*256*2 = 1179648
#define OFF_W1L  1179648UL
#define OFF_W2H  2359296UL
#define OFF_W2L  3538944UL
#define OFF_WRH  4718592UL    // 9*32*256*2 = 147456
#define OFF_WRL  4866048UL
#define OFF_I0H  5013504UL    // 2*4096*256*2 = 4194304  (aliased as conv2-out F after conv1)
#define OFF_I0L  9207808UL
#define OFF_I1H  13402112UL
#define OFF_I1L  14450688UL
#define OFF_I2H  15499264UL
#define OFF_I2L  15761408UL
#define OFF_L3F  16023552UL   // f32 CHW 2*256*1024*4 = 2097152
#define OFF_H0H  18120704UL
#define OFF_H0L  22315008UL
#define OFF_H1H  26509312UL
#define OFF_H1L  27557888UL
#define OFF_H2H  28606464UL
#define OFF_H2L  28868608UL
#define OFF_LOGITS 29130752UL // 2*16128*4 = 129024
#define OFF_TVALS  29259776UL // 516096
#define OFF_SKEY   29775872UL // 129024
#define OFF_COORDS 29904896UL // 3840
#define OFF_BN     29908992UL // 4096
#define OFF_HIST   29917184UL // 6*2048*4 = 49152
#define OFF_P0     29966336UL // 2 * 10752*256*4 = 22020096
#define WS_NEED2   51986432UL

// out layout: dets[2][3][32][5] @0 (960) | mask[2][3][32] @960 (192) | rois @1152

// ---------------- prep: weight split (coalesced) + BN fold + hist zero ----------------
__global__ __launch_bounds__(256) void prep_w_kernel(
    const float* __restrict__ hw1, const float* __restrict__ hw2,
    const float* __restrict__ clsw, const float* __restrict__ locw,
    const float* __restrict__ hg1, const float* __restrict__ hb1,
    const float* __restrict__ hm1, const float* __restrict__ hv1,
    const float* __restrict__ hg2, const float* __restrict__ hb2,
    const float* __restrict__ hm2, const float* __restrict__ hv2,
    char* __restrict__ ws)
{
  if (blockIdx.x == 0) {
    int t = threadIdx.x;
    float* inv1 = (float*)(ws + OFF_BN);
    float* beta1 = inv1 + 256;
    float* inv2 = inv1 + 512;
    float* beta2 = inv1 + 768;
    float i1 = (float)((double)hg1[t] / sqrt((double)hv1[t] + 1e-5));
    inv1[t] = i1;
    beta1[t] = hb1[t] - hm1[t] * i1;
    float i2 = (float)((double)hg2[t] / sqrt((double)hv2[t] + 1e-5));
    inv2[t] = i2;
    beta2[t] = hb2[t] - hm2[t] * i2;
  } else if (blockIdx.x <= 48) {
    ((unsigned int*)(ws + OFF_HIST))[(blockIdx.x - 1) * 256 + threadIdx.x] = 0u;
  }
  _Float16* w1h = (_Float16*)(ws + OFF_W1H);
  _Float16* w1l = (_Float16*)(ws + OFF_W1L);
  _Float16* w2h = (_Float16*)(ws + OFF_W2H);
  _Float16* w2l = (_Float16*)(ws + OFF_W2L);
  _Float16* wrh = (_Float16*)(ws + OFF_WRH);
  _Float16* wrl = (_Float16*)(ws + OFF_WRL);
  const int TOT2 = 2 * 65536 + 8192;   // (oc,ic) pairs
  for (int e = blockIdx.x * 256 + threadIdx.x; e < TOT2; e += gridDim.x * 256) {
    const float* src; _Float16 *dh, *dl; int di, plane;
    if (e < 65536) {
      src = hw1 + (size_t)e * 9; dh = w1h; dl = w1l; di = e; plane = 65536;
    } else if (e < 131072) {
      int e2 = e - 65536;
      src = hw2 + (size_t)e2 * 9; dh = w2h; dl = w2l; di = e2; plane = 65536;
    } else {
      int e3 = e - 131072;
      int oc = e3 >> 8;
      dh = wrh; dl = wrl; di = e3; plane = 8192;
      if (oc < 3) src = clsw + (size_t)e3 * 9;
      else if (oc < 15) src = locw + (size_t)(e3 - 768) * 9;
      else src = nullptr;
    }
    #pragma unroll
    for (int dydx = 0; dydx < 9; ++dydx) {
      float val = src ? src[dydx] : 0.f;
      _Float16 h, l;
      split2(val, h, l);
      dh[(size_t)dydx * plane + di] = h;
      dl[(size_t)dydx * plane + di] = l;
    }
  }
}

// ---------------- fuse body (shared by both fuse kernels) ----------------
__device__ __forceinline__ void fuse_body(
    float T[32][65],
    const float* __restrict__ a, const float* __restrict__ bUp,
    float* __restrict__ f32chw, _Float16* __restrict__ oH, _Float16* __restrict__ oL,
    int H, int logW, int bx, int img)
{
  int HW = H * H;
  const float* ap = a + (size_t)img * 256 * HW;
  const float* bp = bUp ? (bUp + (size_t)img * 256 * (HW >> 2)) : nullptr;
  float* fp = f32chw ? (f32chw + (size_t)img * 256 * HW) : nullptr;
  _Float16* oHp = oH + (size_t)img * HW * 256;
  _Float16* oLp = oL + (size_t)img * HW * 256;
  int p0 = bx * 64;
  int tid = threadIdx.x;
  int px = tid & 63, cg = tid >> 6;
  int gp = p0 + px;
  int y = gp >> logW, x = gp & (H - 1);
  int px2 = tid >> 2, q = tid & 3;
  for (int c0 = 0; c0 < 256; c0 += 32) {
    #pragma unroll
    for (int cc = 0; cc < 8; ++cc) {
      int c = c0 + cg * 8 + cc;
      float v = ap[(size_t)c * HW + gp];
      if (bp) v += bp[(size_t)c * (HW >> 2) + (y >> 1) * (H >> 1) + (x >> 1)];
      if (fp) fp[(size_t)c * HW + gp] = v;
      T[cg * 8 + cc][px] = v;
    }
    __syncthreads();
    {
      size_t oa = (size_t)(p0 + px2) * 256 + c0 + q * 8;
      f16x8 hs, ls;
      #pragma unroll
      for (int j = 0; j < 8; ++j) {
        float v = T[q * 8 + j][px2];
        _Float16 h, l;
        split2(v, h, l);
        hs[j] = h; ls[j] = l;
      }
      *(f16x8*)&oHp[oa] = hs;
      *(f16x8*)&oLp[oa] = ls;
    }
    __syncthreads();
  }
}

// merged small-level fuse: x<4 -> l4->i2 (H=16); x>=4 -> l3+up(l4)->i1,l3f (H=32)
__global__ __launch_bounds__(256) void fuse_small_kernel(
    const float* __restrict__ layer4, const float* __restrict__ layer3,
    float* __restrict__ l3f,
    _Float16* __restrict__ i2H, _Float16* __restrict__ i2L,
    _Float16* __restrict__ i1H, _Float16* __restrict__ i1L)
{
  __shared__ float T[32][65];
  int img = blockIdx.y;
  if (blockIdx.x < 4)
    fuse_body(T, layer4, nullptr, nullptr, i2H, i2L, 16, 4, blockIdx.x, img);
  else
    fuse_body(T, layer3, layer4, l3f, i1H, i1L, 32, 5, blockIdx.x - 4, img);
}

__global__ __launch_bounds__(256) void fuse_kernel(
    const float* __restrict__ a, const float* __restrict__ bUp,
    float* __restrict__ f32chw, _Float16* __restrict__ oH, _Float16* __restrict__ oL,
    int H, int logW)
{
  __shared__ float T[32][65];
  fuse_body(T, a, bUp, f32chw, oH, oL, H, logW, blockIdx.x, blockIdx.y);
}

// ---------------- MFMA implicit-GEMM 3x3 conv: 64px x 64oc per WAVE, XCD-swizzled 1D grid ----------------
// 1D grid: wid -> combo = wid % (parts*OCG*2), tile = wid / cc.
// combo packs (yv, img); XCD round-robin => each XCD owns one combo's weight slab.
struct CArgs {
  const _Float16* inH[3]; const _Float16* inL[3];   // fp16 HWC per level
  const _Float16* wH; const _Float16* wL;           // [9][OCW][256]
  _Float16* outH[3]; _Float16* outL[3];             // fp16 HWC outs (mode 0, parts==1)
  const float* inv; const float* beta;              // BN folded
  float* logits; float* tvals;                      // mode 2, parts==1
  float* pbase; size_t pstride;                     // partial buffers (parts>1)
  int mode; int parts;
};

#define PXS 40   // LDS pixel stride in shorts

template<int OCW, int WN, int NI>
__global__ __launch_bounds__(WN * 64, 2) void conv_mfma_kernel(CArgs a)
{
  constexpr int NT = WN * 64;
  constexpr int NOC = WN * NI * 32;
  constexpr int OCG = OCW / NOC;
  __shared__ _Float16 Ph[2][100 * PXS], Pl[2][100 * PXS];

  int cc = a.parts * OCG * 2;
  int wid = blockIdx.x;
  int combo = wid % cc;
  int bt = wid / cc;
  int yv = combo >> 1;
  int img = combo & 1;

  int lvl, tile;
  if (bt < 64) { lvl = 0; tile = bt; }
  else if (bt < 80) { lvl = 1; tile = bt - 64; }
  else { lvl = 2; tile = bt - 80; }
  int H = (lvl == 0) ? 64 : ((lvl == 1) ? 32 : 16);
  int HW = H * H;
  int tpr = H >> 3;
  int ty0 = (tile / tpr) * 8, tx0 = (tile % tpr) * 8;

  int part = yv / OCG;
  int ocb = (yv % OCG) * NOC;
  int nicb = 8 / a.parts;
  int icb0 = part * nicb;
  float* pout = (a.parts > 1) ? (a.pbase + (size_t)part * a.pstride) : nullptr;

  const _Float16* inH = a.inH[lvl] + (size_t)img * HW * 256;
  const _Float16* inL = a.inL[lvl] + (size_t)img * HW * 256;

  int tid = threadIdx.x;
  int lane = tid & 63, wn = tid >> 6;
  int row = lane & 31, khalf = lane >> 5;
  int abase[2];
  #pragma unroll
  for (int mi = 0; mi < 2; ++mi) {
    int m = mi * 32 + row;
    abase[mi] = ((m >> 3) * 10 + (m & 7)) * PXS + khalf * 8;
  }

  const _Float16* wHb = a.wH + (size_t)(ocb + wn * NI * 32 + row) * 256 + khalf * 8 + icb0 * 32;
  const _Float16* wLb = a.wL + (size_t)(ocb + wn * NI * 32 + row) * 256 + khalf * 8 + icb0 * 32;

  f32x16 acc1[2][NI], acc2[2][NI];
  #pragma unroll
  for (int mi = 0; mi < 2; ++mi)
    #pragma unroll
    for (int ni = 0; ni < NI; ++ni)
      #pragma unroll
      for (int j = 0; j < 16; ++j) { acc1[mi][ni][j] = 0.f; acc2[mi][ni][j] = 0.f; }

  auto stage = [&](int icb, int buf) {
    for (int u = tid; u < 400; u += NT) {
      int pxl = u >> 2, icq = u & 3;
      int py = pxl / 10, pxx = pxl - py * 10;
      int gy = ty0 + py - 1, gx = tx0 + pxx - 1;
      int lo = pxl * PXS + icq * 8;
      if ((unsigned)gy < (unsigned)H && (unsigned)gx < (unsigned)H) {
        size_t ga = (size_t)(gy * H + gx) * 256 + icb * 32 + icq * 8;
        *(f16x8*)&Ph[buf][lo] = *(const f16x8*)&inH[ga];
        *(f16x8*)&Pl[buf][lo] = *(const f16x8*)&inL[ga];
      } else {
        f16x8 z;
        #pragma unroll
        for (int j = 0; j < 8; ++j) z[j] = (_Float16)0.f;
        *(f16x8*)&Ph[buf][lo] = z;
        *(f16x8*)&Pl[buf][lo] = z;
      }
    }
  };

  stage(icb0, 0);
  __syncthreads();

  for (int rel = 0; rel < nicb; ++rel) {
    int cur = rel & 1;
    if (rel < nicb - 1) stage(icb0 + rel + 1, cur ^ 1);
    #pragma unroll
    for (int dydx = 0; dydx < 9; ++dydx) {
      int sh = ((dydx / 3) * 10 + (dydx % 3)) * PXS;
      #pragma unroll
      for (int k2 = 0; k2 < 2; ++k2) {
        f16x8 bh[NI], bl[NI], ah[2], al[2];
        #pragma unroll
        for (int ni = 0; ni < NI; ++ni) {
          size_t ga = (size_t)dydx * OCW * 256 + (size_t)ni * 32 * 256 + rel * 32 + k2 * 16;
          bh[ni] = *(const f16x8*)&wHb[ga];
          bl[ni] = *(const f16x8*)&wLb[ga];
        }
        #pragma unroll
        for (int mi = 0; mi < 2; ++mi) {
          int off = abase[mi] + sh + k2 * 16;
          ah[mi] = *(const f16x8*)&Ph[cur][off];
          al[mi] = *(const f16x8*)&Pl[cur][off];
        }
        #pragma unroll
        for (int mi = 0; mi < 2; ++mi)
          #pragma unroll
          for (int ni = 0; ni < NI; ++ni) {
            acc1[mi][ni] = __builtin_amdgcn_mfma_f32_32x32x16_f16(ah[mi], bh[ni], acc1[mi][ni], 0, 0, 0);
            acc2[mi][ni] = __builtin_amdgcn_mfma_f32_32x32x16_f16(ah[mi], bl[ni], acc2[mi][ni], 0, 0, 0);
            acc2[mi][ni] = __builtin_amdgcn_mfma_f32_32x32x16_f16(al[mi], bh[ni], acc2[mi][ni], 0, 0, 0);
          }
      }
    }
    __syncthreads();
  }

  // ---- epilogue ----
  int poffv = (lvl == 0) ? 0 : ((lvl == 1) ? 4096 : 5120);
  #pragma unroll
  for (int mi = 0; mi < 2; ++mi)
    #pragma unroll
    for (int ni = 0; ni < NI; ++ni) {
      int oc = ocb + wn * NI * 32 + ni * 32 + row;
      float v[16];
      #pragma unroll
      for (int r = 0; r < 16; ++r) v[r] = acc1[mi][ni][r] + acc2[mi][ni][r] * (1.f / 4096.f);
      if (pout) {
        float* pp = pout + (size_t)(img * 5376 + poffv) * OCW;
        #pragma unroll
        for (int r = 0; r < 16; ++r) {
          int ml = (r & 3) + 8 * (r >> 2) + 4 * khalf;
          int m = mi * 32 + ml;
          int y = ty0 + (m >> 3), x = tx0 + (m & 7);
          __builtin_nontemporal_store(v[r], &pp[(size_t)(y * H + x) * OCW + oc]);
        }
      } else if (a.mode == 0) {
        _Float16* outH = a.outH[lvl] + (size_t)img * HW * 256;
        _Float16* outL = a.outL[lvl] + (size_t)img * HW * 256;
        float iv = a.inv[oc], bb = a.beta[oc];
        #pragma unroll
        for (int r = 0; r < 16; ++r) {
          int ml = (r & 3) + 8 * (r >> 2) + 4 * khalf;
          int m = mi * 32 + ml;
          int y = ty0 + (m >> 3), x = tx0 + (m & 7);
          float vv = v[r] * iv + bb;
          vv = (vv >= 0.f) ? vv : 0.01f * vv;
          _Float16 h, l;
          split2(vv, h, l);
          size_t oa = (size_t)(y * H + x) * 256 + oc;
          outH[oa] = h;
          outL[oa] = l;
        }
      } else {
        if (oc < 15) {
          int abse = (lvl == 0) ? 0 : ((lvl == 1) ? 12288 : 15360);
          #pragma unroll
          for (int r = 0; r < 16; ++r) {
            int ml = (r & 3) + 8 * (r >> 2) + 4 * khalf;
            int m = mi * 32 + ml;
            int y = ty0 + (m >> 3), x = tx0 + (m & 7);
            int gi = img * 16128 + abse + (y * H + x) * 3;
            if (oc < 3) a.logits[gi + oc] = v[r];
            else { int r2 = oc - 3; a.tvals[(size_t)(gi + (r2 >> 2)) * 4 + (r2 & 3)] = v[r]; }
          }
        }
      }
    }
}

// ---------------- combine: p0+p1 -> BN -> lrelu -> split2 HWC (fixed 2-part) ----------------
__global__ __launch_bounds__(256) void combine_head_kernel(
    const float* __restrict__ p0, const float* __restrict__ p1,
    const float* __restrict__ inv, const float* __restrict__ beta,
    _Float16* __restrict__ oH0, _Float16* __restrict__ oL0,
    _Float16* __restrict__ oH1, _Float16* __restrict__ oL1,
    _Float16* __restrict__ oH2, _Float16* __restrict__ oL2)
{
  int g = blockIdx.x * 256 + threadIdx.x;      // 10752*32 total
  int pixel = g >> 5, q = g & 31;
  size_t base = (size_t)pixel * 256 + q * 8;
  int img = pixel / 5376, rem = pixel - img * 5376;
  int lvl = (rem < 4096) ? 0 : ((rem < 5120) ? 1 : 2);
  int poffv = (lvl == 0) ? 0 : ((lvl == 1) ? 4096 : 5120);
  int HW = (lvl == 0) ? 4096 : ((lvl == 1) ? 1024 : 256);
  int lpx = rem - poffv;
  size_t oa = ((size_t)img * HW + lpx) * 256 + q * 8;
  _Float16* oH = ((lvl == 0) ? oH0 : ((lvl == 1) ? oH1 : oH2)) + oa;
  _Float16* oL = ((lvl == 0) ? oL0 : ((lvl == 1) ? oL1 : oL2)) + oa;
  f16x8 hs, ls;
  #pragma unroll
  for (int j = 0; j < 8; ++j) {
    int oc = q * 8 + j;
    float a0 = __builtin_nontemporal_load(&p0[base + j]);
    float a1 = __builtin_nontemporal_load(&p1[base + j]);
    float vv = (a0 + a1) * inv[oc] + beta[oc];
    vv = (vv >= 0.f) ? vv : 0.01f * vv;
    _Float16 h, l;
    split2(vv, h, l);
    hs[j] = h; ls[j] = l;
  }
  *(f16x8*)oH = hs;
  *(f16x8*)oL = ls;
}

// ---------------- decode helper ----------------
__device__ __forceinline__ void decode_one4(const float t0, const float t1,
                                            const float t2v, const float t3v,
                                            const float* __restrict__ anch, int i,
                                            float& x1, float& y1, float& x2, float& y2)
{
  float a0 = anch[i * 4 + 0], a1 = anch[i * 4 + 1], a2 = anch[i * 4 + 2], a3 = anch[i * 4 + 3];
  float aw = a2 - a0, ah = a3 - a1;
  float xx = a0 + t0 * aw;
  float yy = a1 + t1 * ah;
  float bw = aw * expf(t2v);
  float bh = ah * expf(t3v);
  x1 = fminf(fmaxf(xx, 0.f), 512.f);
  y1 = fminf(fmaxf(yy, 0.f), 512.f);
  x2 = fminf(fmaxf(xx + bw, 0.f), 512.f);
  y2 = fminf(fmaxf(yy + bh, 0.f), 512.f);
}

__device__ __forceinline__ void decode_one(const float* __restrict__ anch,
                                           const float* __restrict__ tv, int i,
                                           float& x1, float& y1, float& x2, float& y2)
{
  decode_one4(tv[i * 4 + 0], tv[i * 4 + 1], tv[i * 4 + 2], tv[i * 4 + 3], anch, i, x1, y1, x2, y2);
}

// ---------------- score kernel: (optional rpn-combine) + keys + 2048-bin hist ----------------
__global__ __launch_bounds__(256) void score_kernel(
    const float* __restrict__ logits, float* __restrict__ tvals,
    const float* __restrict__ praw,
    const float* __restrict__ anch0, const float* __restrict__ anch1, const float* __restrict__ anch2,
    unsigned int* __restrict__ skey, unsigned int* __restrict__ hist)
{
  int g = blockIdx.x * 256 + threadIdx.x;
  if (g >= 2 * 16128) return;
  int img = g / 16128, r = g - img * 16128;
  int lvl = (r < 12288) ? 0 : ((r < 15360) ? 1 : 2);
  int abase = (lvl == 0) ? 0 : ((lvl == 1) ? 12288 : 15360);
  int stride = (lvl == 0) ? 8 : ((lvl == 1) ? 16 : 32);
  const float* anch = (lvl == 0) ? anch0 : ((lvl == 1) ? anch1 : anch2);
  int i = r - abase;
  float lv, t0, t1, t2v, t3v;
  if (praw) {
    int poffv = (lvl == 0) ? 0 : ((lvl == 1) ? 4096 : 5120);
    int p = i / 3, a = i - p * 3;
    size_t pb = ((size_t)(img * 5376 + poffv) + p) * 32;
    float s[5] = {0.f, 0.f, 0.f, 0.f, 0.f};
    #pragma unroll
    for (int k = 0; k < 4; ++k) {
      const float* pp = praw + (size_t)k * 10752 * 32 + pb;
      s[0] += __builtin_nontemporal_load(&pp[a]);
      #pragma unroll
      for (int c = 0; c < 4; ++c) s[1 + c] += __builtin_nontemporal_load(&pp[3 + a * 4 + c]);
    }
    lv = s[0]; t0 = s[1]; t1 = s[2]; t2v = s[3]; t3v = s[4];
    float* tw = tvals + (size_t)g * 4;
    tw[0] = t0; tw[1] = t1; tw[2] = t2v; tw[3] = t3v;
  } else {
    lv = logits[g];
    const float* tv = tvals + (size_t)g * 4;
    t0 = tv[0]; t1 = tv[1]; t2v = tv[2]; t3v = tv[3];
  }
  float sc = 1.f / (1.f + expf(-lv));
  float x1, y1, x2, y2;
  decode_one4(t0, t1, t2v, t3v, anch, i, x1, y1, x2, y2);
  float minsz = 2.0f * (float)stride;
  bool valid = (sc > 0.5f) && ((x2 - x1) >= minsz) && ((y2 - y1) >= minsz);
  unsigned int key = valid ? __float_as_uint(sc) : 0u;
  skey[g] = key;
  if (valid)
    atomicAdd(&hist[(img * 3 + lvl) * 2048 + ((key & 0xFFFFFFu) >> 13)], 1u);
}

// ---------------- postproc: bin-threshold -> collect -> rank-sort -> ballot NMS -> outputs ----------------
__global__ __launch_bounds__(256) void postproc_kernel(
    const float* __restrict__ tvals,
    const float* __restrict__ anch0, const float* __restrict__ anch1, const float* __restrict__ anch2,
    const unsigned int* __restrict__ skey, const unsigned int* __restrict__ hist,
    float* __restrict__ dout, int* __restrict__ coords)
{
  int lvl = blockIdx.x, img = blockIdx.y;
  int N = (lvl == 0) ? 12288 : ((lvl == 1) ? 3072 : 768);
  int stride = (lvl == 0) ? 8 : ((lvl == 1) ? 16 : 32);
  int abase = (lvl == 0) ? 0 : ((lvl == 1) ? 12288 : 15360);
  const float* anch = (lvl == 0) ? anch0 : ((lvl == 1) ? anch1 : anch2);
  const float* tv = tvals + (size_t)(img * 16128 + abase) * 4;
  const unsigned int* sk = skey + img * 16128 + abase;
  int tx = threadIdx.x;

  __shared__ int tot[256];
  __shared__ int sh_bin, sh_V;
  __shared__ ull slist[1024];
  __shared__ int scnt;
  __shared__ ull skey64[256];
  __shared__ float bx0[256], bx1[256], bx2[256], bx3[256], bar[256], bsc[256];
  __shared__ ull colT[256][4];
  __shared__ ull kinit[4], kfin[4];
  __shared__ unsigned char bkeepArr[256];
  __shared__ int sel[32];

  const unsigned int* hp = hist + (img * 3 + lvl) * 2048;
  unsigned int hloc[8];
  #pragma unroll
  for (int j = 0; j < 8; ++j) hloc[j] = hp[tx * 8 + j];
  int sl[9]; sl[8] = 0;
  #pragma unroll
  for (int j = 7; j >= 0; --j) sl[j] = sl[j + 1] + (int)hloc[j];
  tot[tx] = sl[0];
  if (tx == 0) { sh_bin = 2048; scnt = 0; }
  __syncthreads();
  int T = 0;
  for (int b = 0; b < 256; ++b) T += (b > tx) ? tot[b] : 0;
  if (tx == 0) sh_V = T + sl[0];
  __syncthreads();
  int V = sh_V;
  int needed = (V < 256) ? V : 256;
  if (needed > 0) {
    #pragma unroll
    for (int j = 0; j < 8; ++j) {
      int suf = T + sl[j];
      int sufn = (j < 7) ? (T + sl[j + 1]) : T;
      if (suf >= needed && sufn < needed) sh_bin = tx * 8 + j;
    }
  }
  #pragma unroll
  for (int q = 0; q < 4; ++q) slist[tx + q * 256] = 0ull;
  __syncthreads();
  int Bstar = sh_bin;

  if (needed > 0) {
    const uint4* sk4 = (const uint4*)sk;
    for (int i4 = tx; i4 < (N >> 2); i4 += 256) {
      uint4 v4 = sk4[i4];
      unsigned int vv[4] = {v4.x, v4.y, v4.z, v4.w};
      #pragma unroll
      for (int q = 0; q < 4; ++q) {
        unsigned int v = vv[q];
        if (v != 0u && (int)((v & 0xFFFFFFu) >> 13) >= Bstar) {
          int p = atomicAdd(&scnt, 1);
          if (p < 1024)
            slist[p] = ((ull)v << 32) | (ull)(0xFFFFFFFFu - (unsigned)(i4 * 4 + q));
        }
      }
    }
  }
  __syncthreads();
  int M = scnt < 1024 ? scnt : 1024;

  skey64[tx] = 0ull;
  __syncthreads();
  for (int it = tx; it < M; it += 256) {
    ull K = slist[it];
    int rank = 0;
    for (int j = 0; j < M; ++j) rank += (slist[j] > K) ? 1 : 0;
    if (rank < 256) skey64[rank] = K;
  }
  __syncthreads();

  {
    ull key = skey64[tx];
    float x1 = 0.f, y1 = 0.f, x2 = 0.f, y2 = 0.f, sc = 0.f;
    if (key != 0ull) {
      sc = __uint_as_float((unsigned int)(key >> 32));
      int idx = (int)(0xFFFFFFFFu - (unsigned int)(key & 0xFFFFFFFFull));
      decode_one(anch, tv, idx, x1, y1, x2, y2);
    }
    bx0[tx] = x1; bx1[tx] = y1; bx2[tx] = x2; bx3[tx] = y2;
    bsc[tx] = sc;
    bar[tx] = (x2 - x1 + 1.f) * (y2 - y1 + 1.f);
    ull b = __ballot(sc > 0.5f);
    if ((tx & 63) == 0) kinit[tx >> 6] = b;
  }
  __syncthreads();

  {
    float xj1 = bx0[tx], yj1 = bx1[tx], xj2 = bx2[tx], yj2 = bx3[tx], aj = bar[tx];
    #pragma unroll
    for (int w = 0; w < 4; ++w) {
      ull rr = 0ull;
      int j0 = w * 64;
      int ie = (tx < j0 + 64) ? tx : (j0 + 64);
      for (int i = j0; i < ie; ++i) {
        float xx1 = fmaxf(xj1, bx0[i]);
        float yy1 = fmaxf(yj1, bx1[i]);
        float xx2 = fminf(xj2, bx2[i]);
        float yy2 = fminf(yj2, bx3[i]);
        float ww = fmaxf(0.f, xx2 - xx1 + 1.f);
        float hh = fmaxf(0.f, yy2 - yy1 + 1.f);
        float inter = ww * hh;
        float ovr = inter / (aj + bar[i] - inter);
        rr |= (ovr > 0.3f) ? (1ull << (i & 63)) : 0ull;
      }
      colT[tx][w] = rr;
    }
  }
  __syncthreads();

  if (tx < 64) {
    int l = tx;
    ull cm[4][4];
    #pragma unroll
    for (int c = 0; c < 4; ++c)
      #pragma unroll
      for (int w = 0; w < 4; ++w) cm[c][w] = colT[l + 64 * c][w];
    int av[4];
    #pragma unroll
    for (int c = 0; c < 4; ++c) av[c] = (int)((kinit[c] >> l) & 1ull);
    for (int cw = 0; cw < 4; ++cw) {
      ull rem = __ballot(av[cw] != 0);
      while (rem) {
        int ib = __builtin_ctzll(rem);
        #pragma unroll
        for (int c = 0; c < 4; ++c) {
          int sup = (int)((cm[c][cw] >> ib) & 1ull);
          av[c] &= sup ^ 1;
        }
        ull ready = __ballot(av[cw] != 0);
        rem = (ib == 63) ? 0ull : (ready & (~0ull << (ib + 1)));
      }
    }
    #pragma unroll
    for (int c = 0; c < 4; ++c) {
      ull bw = __ballot(av[c] != 0);
      if (l == 0) kfin[c] = bw;
      bkeepArr[l + 64 * c] = (unsigned char)av[c];
    }
  }
  __syncthreads();

  {
    int r = tx;
    int m = bkeepArr[r];
    int K = 0, before = 0;
    #pragma unroll
    for (int c = 0; c < 4; ++c) {
      int pc = __popcll(kfin[c]);
      K += pc;
      if (r >= (c + 1) * 64) before += pc;
      else if (r > c * 64) before += __popcll(kfin[c] & ((1ull << (r - c * 64)) - 1ull));
    }
    int rank = m ? before : (K + r - before);
    if (rank < 32) sel[rank] = r;
  }
  __syncthreads();

  if (tx < 32) {
    int r = sel[tx];
    int m = bkeepArr[r];
    int ob = (img * 3 + lvl) * 32 + tx;
    float d0 = 0.f, d1 = 0.f, d2 = 0.f, d3 = 0.f, d4 = 0.f;
    int c0 = 0, c1 = 0, c2 = 2, c3 = 2;
    if (m) {
      d0 = bx0[r]; d1 = bx1[r]; d2 = bx2[r]; d3 = bx3[r]; d4 = bsc[r];
      c0 = ((int)d0) / stride; c1 = ((int)d1) / stride;
      c2 = ((int)d2) / stride; c3 = ((int)d3) / stride;
    }
    dout[ob * 5 + 0] = d0; dout[ob * 5 + 1] = d1; dout[ob * 5 + 2] = d2;
    dout[ob * 5 + 3] = d3; dout[ob * 5 + 4] = d4;
    dout[960 + ob] = m ? 1.f : 0.f;
    coords[ob * 5 + 0] = c0; coords[ob * 5 + 1] = c1;
    coords[ob * 5 + 2] = c2; coords[ob * 5 + 3] = c3;
    coords[ob * 5 + 4] = m;
  }
}

// ---------------- ROI adaptive 7x7 maxpool: one block per (roi, bin) ----------------
__global__ __launch_bounds__(256) void roipool_kernel(
    const _Float16* __restrict__ fh0, const _Float16* __restrict__ fl0,
    const _Float16* __restrict__ fh1, const _Float16* __restrict__ fl1,
    const _Float16* __restrict__ fh2, const _Float16* __restrict__ fl2,
    const int* __restrict__ coords, float* __restrict__ dout)
{
  int bx = blockIdx.x;
  int slot = bx / 49, bin = bx - slot * 49;
  int yi = bin / 7, xi = bin - yi * 7;
  int lvl = blockIdx.y, img = blockIdx.z;
  int ob = (img * 3 + lvl) * 32 + slot;
  int c = threadIdx.x;
  const int* cw = coords + ob * 5;
  float* outp = dout + 1152 + (size_t)ob * 256 * 49 + (size_t)c * 49 + yi * 7 + xi;
  int m = cw[4];
  if (!m) { *outp = 0.f; return; }
  int H = (lvl == 0) ? 64 : ((lvl == 1) ? 32 : 16);
  const _Float16* fh = ((lvl == 0) ? fh0 : ((lvl == 1) ? fh1 : fh2)) + (size_t)img * H * H * 256;
  const _Float16* fl = ((lvl == 0) ? fl0 : ((lvl == 1) ? fl1 : fl2)) + (size_t)img * H * H * 256;
  int lox = cw[0], loy = cw[1], hix = cw[2], hiy = cw[3];
  int Lx = hix - lox, Ly = hiy - loy;
  int ys = loy + (yi * Ly) / 7;
  int ye = loy + ((yi + 1) * Ly + 6) / 7;
  int xs = lox + (xi * Lx) / 7;
  int xe = lox + ((xi + 1) * Lx + 6) / 7;
  float mx = -3.402823466e+38f;
  for (int y = ys; y < ye; ++y) {
    size_t rowb = ((size_t)y * H) * 256 + c;
    for (int x = xs; x < xe; ++x) {
      size_t idx = rowb + (size_t)x * 256;
      float v = (float)fh[idx] + (float)fl[idx] * (1.f / 4096.f);
      mx = fmaxf(mx, v);
    }
  }
  *outp = mx;
}

// ---------------- host ----------------
extern "C" void kernel_launch(void* const* d_in, const int* in_sizes, int n_in,
                              void* d_out, int out_size, void* d_ws, size_t ws_size,
                              hipStream_t stream)
{
  (void)in_sizes; (void)n_in; (void)out_size;
  char* ws = (char*)d_ws;
  const float* layer2 = (const float*)d_in[0];
  const float* layer3 = (const float*)d_in[1];
  const float* layer4 = (const float*)d_in[2];
  const float* anch2  = (const float*)d_in[3];
  const float* anch3  = (const float*)d_in[4];
  const float* anch4  = (const float*)d_in[5];
  const float* hw1 = (const float*)d_in[6];
  const float* hg1 = (const float*)d_in[7];
  const float* hb1 = (const float*)d_in[8];
  const float* hm1 = (const float*)d_in[9];
  const float* hv1 = (const float*)d_in[10];
  const float* hw2 = (const float*)d_in[11];
  const float* hg2 = (const float*)d_in[12];
  const float* hb2 = (const float*)d_in[13];
  const float* hm2 = (const float*)d_in[14];
  const float* hv2 = (const float*)d_in[15];
  const float* clsw = (const float*)d_in[16];
  const float* locw = (const float*)d_in[17];
  float* dout = (float*)d_out;

  int hparts = (ws_size >= WS_NEED2) ? 2 : 1;
  int rparts = (ws_size >= WS_NEED2) ? 4 : 1;

  _Float16* i0H = (_Float16*)(ws + OFF_I0H);
  _Float16* i0L = (_Float16*)(ws + OFF_I0L);
  _Float16* i1H = (_Float16*)(ws + OFF_I1H);
  _Float16* i1L = (_Float16*)(ws + OFF_I1L);
  _Float16* i2H = (_Float16*)(ws + OFF_I2H);
  _Float16* i2L = (_Float16*)(ws + OFF_I2L);
  float* l3f = (float*)(ws + OFF_L3F);
  _Float16* h0H = (_Float16*)(ws + OFF_H0H);
  _Float16* h0L = (_Float16*)(ws + OFF_H0L);
  _Float16* h1H = (_Float16*)(ws + OFF_H1H);
  _Float16* h1L = (_Float16*)(ws + OFF_H1L);
  _Float16* h2H = (_Float16*)(ws + OFF_H2H);
  _Float16* h2L = (_Float16*)(ws + OFF_H2L);
  float* logits = (float*)(ws + OFF_LOGITS);
  float* tvals  = (float*)(ws + OFF_TVALS);
  unsigned int* skey = (unsigned int*)(ws + OFF_SKEY);
  int* coords = (int*)(ws + OFF_COORDS);
  float* bn = (float*)(ws + OFF_BN);
  float* inv1 = bn; float* beta1 = bn + 256; float* inv2 = bn + 512; float* beta2 = bn + 768;
  unsigned int* hist = (unsigned int*)(ws + OFF_HIST);
  float* P0 = (float*)(ws + OFF_P0);
  float* P1 = P0 + 10752UL * 256UL;

  prep_w_kernel<<<576, 256, 0, stream>>>(hw1, hw2, clsw, locw,
                                         hg1, hb1, hm1, hv1, hg2, hb2, hm2, hv2, ws);

  fuse_small_kernel<<<dim3(20, 2), 256, 0, stream>>>(layer4, layer3, l3f, i2H, i2L, i1H, i1L);
  fuse_kernel<<<dim3(64, 2), 256, 0, stream>>>(layer2, l3f, nullptr, i0H, i0L, 64, 6);

  CArgs c1;
  c1.inH[0] = i0H; c1.inH[1] = i1H; c1.inH[2] = i2H;
  c1.inL[0] = i0L; c1.inL[1] = i1L; c1.inL[2] = i2L;
  c1.wH = (const _Float16*)(ws + OFF_W1H); c1.wL = (const _Float16*)(ws + OFF_W1L);
  c1.outH[0] = h0H; c1.outH[1] = h1H; c1.outH[2] = h2H;
  c1.outL[0] = h0L; c1.outL[1] = h1L; c1.outL[2] = h2L;
  c1.inv = inv1; c1.beta = beta1;
  c1.logits = nullptr; c1.tvals = nullptr;
  c1.pbase = P0; c1.pstride = 10752UL * 256UL;
  c1.mode = 0; c1.parts = hparts;
  conv_mfma_kernel<256, 2, 2><<<84 * hparts * 2 * 2, 128, 0, stream>>>(c1);
  if (hparts > 1)
    combine_head_kernel<<<1344, 256, 0, stream>>>(P0, P1, inv1, beta1,
                                                  h0H, h0L, h1H, h1L, h2H, h2L);

  _Float16* f0H = i0H; _Float16* f0L = i0L;
  _Float16* f1H = i1H; _Float16* f1L = i1L;
  _Float16* f2H = i2H; _Float16* f2L = i2L;

  CArgs c2;
  c2.inH[0] = h0H; c2.inH[1] = h1H; c2.inH[2] = h2H;
  c2.inL[0] = h0L; c2.inL[1] = h1L; c2.inL[2] = h2L;
  c2.wH = (const _Float16*)(ws + OFF_W2H); c2.wL = (const _Float16*)(ws + OFF_W2L);
  c2.outH[0] = f0H; c2.outH[1] = f1H; c2.outH[2] = f2H;
  c2.outL[0] = f0L; c2.outL[1] = f1L; c2.outL[2] = f2L;
  c2.inv = inv2; c2.beta = beta2;
  c2.logits = nullptr; c2.tvals = nullptr;
  c2.pbase = P0; c2.pstride = 10752UL * 256UL;
  c2.mode = 0; c2.parts = hparts;
  conv_mfma_kernel<256, 2, 2><<<84 * hparts * 2 * 2, 128, 0, stream>>>(c2);
  if (hparts > 1)
    combine_head_kernel<<<1344, 256, 0, stream>>>(P0, P1, inv2, beta2,
                                                  f0H, f0L, f1H, f1L, f2H, f2L);

  CArgs cr;
  cr.inH[0] = f0H; cr.inH[1] = f1H; cr.inH[2] = f2H;
  cr.inL[0] = f0L; cr.inL[1] = f1L; cr.inL[2] = f2L;
  cr.wH = (const _Float16*)(ws + OFF_WRH); cr.wL = (const _Float16*)(ws + OFF_WRL);
  cr.outH[0] = nullptr; cr.outH[1] = nullptr; cr.outH[2] = nullptr;
  cr.outL[0] = nullptr; cr.outL[1] = nullptr; cr.outL[2] = nullptr;
  cr.inv = nullptr; cr.beta = nullptr;
  cr.logits = logits; cr.tvals = tvals;
  cr.pbase = P0; cr.pstride = 10752UL * 32UL;
  cr.mode = 2; cr.parts = rparts;
  conv_mfma_kernel<32, 1, 1><<<84 * rparts * 2, 64, 0, stream>>>(cr);

  score_kernel<<<126, 256, 0, stream>>>(logits, tvals, (rparts > 1) ? P0 : nullptr,
                                        anch2, anch3, anch4, skey, hist);
  postproc_kernel<<<dim3(3, 2), 256, 0, stream>>>(tvals, anch2, anch3, anch4, skey, hist, dout, coords);
  roipool_kernel<<<dim3(32 * 49, 3, 2), 256, 0, stream>>>(f0H, f0L, f1H, f1L, f2H, f2L, coords, dout);
}